// Round 1
// baseline (3496.842 us; speedup 1.0000x reference)
//
#include <hip/hip_runtime.h>
#include <math.h>

#define S_LEN 2048
#define BATCH 2
#define NH 16
#define NKV 4
#define DKQ 128
#define DVV 128
#define HID 2048
#define QKV_DIM 3072
#define M_TOK 4096

__device__ __forceinline__ float sigmoidf_(float x) { return 1.f / (1.f + __expf(-x)); }

// ---------------- GEMM NT: C[M,N] = A[M,K] * B[N,K]^T (both K-contiguous) ----------------
__global__ __launch_bounds__(256) void gemm_nt128(const float* __restrict__ A,
                                                  const float* __restrict__ B,
                                                  float* __restrict__ C,
                                                  int M, int N, int K) {
  __shared__ float As[16][132];
  __shared__ float Bs[16][132];
  int bm = blockIdx.y * 128, bn = blockIdx.x * 128;
  int tid = threadIdx.x;
  int tm = tid >> 4, tn = tid & 15;
  float acc[8][8];
#pragma unroll
  for (int i = 0; i < 8; ++i)
#pragma unroll
    for (int j = 0; j < 8; ++j) acc[i][j] = 0.f;

  for (int k0 = 0; k0 < K; k0 += 16) {
#pragma unroll
    for (int i = 0; i < 2; ++i) {
      int F = tid + 256 * i;
      int r = F >> 2, kq = (F & 3) * 4;
      float4 av = *(const float4*)&A[(size_t)(bm + r) * K + k0 + kq];
      float4 bv = *(const float4*)&B[(size_t)(bn + r) * K + k0 + kq];
      As[kq + 0][r] = av.x; As[kq + 1][r] = av.y; As[kq + 2][r] = av.z; As[kq + 3][r] = av.w;
      Bs[kq + 0][r] = bv.x; Bs[kq + 1][r] = bv.y; Bs[kq + 2][r] = bv.z; Bs[kq + 3][r] = bv.w;
    }
    __syncthreads();
#pragma unroll
    for (int kk = 0; kk < 16; ++kk) {
      float a[8], b[8];
      *(float4*)&a[0] = *(const float4*)&As[kk][tm * 4];
      *(float4*)&a[4] = *(const float4*)&As[kk][64 + tm * 4];
      *(float4*)&b[0] = *(const float4*)&Bs[kk][tn * 4];
      *(float4*)&b[4] = *(const float4*)&Bs[kk][64 + tn * 4];
#pragma unroll
      for (int i = 0; i < 8; ++i)
#pragma unroll
        for (int j = 0; j < 8; ++j) acc[i][j] += a[i] * b[j];
    }
    __syncthreads();
  }
#pragma unroll
  for (int i = 0; i < 8; ++i) {
    int m = bm + (i < 4 ? tm * 4 + i : 64 + tm * 4 + (i - 4));
#pragma unroll
    for (int jh = 0; jh < 2; ++jh) {
      int n = bn + jh * 64 + tn * 4;
      float4 v = make_float4(acc[i][jh * 4 + 0], acc[i][jh * 4 + 1],
                             acc[i][jh * 4 + 2], acc[i][jh * 4 + 3]);
      *(float4*)&C[(size_t)m * N + n] = v;
    }
  }
}

// ---------------- gk/b projections -> alpha [B,H,S], beta [B,H,S] ----------------
__global__ __launch_bounds__(256) void gkb_kernel(const float* __restrict__ X,
                                                  const float* __restrict__ gk_w,
                                                  const float* __restrict__ b_w,
                                                  float* __restrict__ al,
                                                  float* __restrict__ be) {
  __shared__ float xs[16][260];
  __shared__ float ws[32][260];
  int tid = threadIdx.x;
  int m0 = blockIdx.x * 16;
  int tl = tid >> 4, n0 = tid & 15;
  float acc0 = 0.f, acc1 = 0.f;
  for (int k0 = 0; k0 < HID; k0 += 256) {
#pragma unroll
    for (int i = 0; i < 4; ++i) {
      int F = i * 256 + tid;
      int r = F >> 6, c4 = (F & 63) * 4;
      *(float4*)&xs[r][c4] = *(const float4*)&X[(size_t)(m0 + r) * HID + k0 + c4];
    }
#pragma unroll
    for (int i = 0; i < 8; ++i) {
      int F = i * 256 + tid;
      int r = F >> 6, c4 = (F & 63) * 4;
      const float* src = (r < 16) ? (gk_w + (size_t)r * HID) : (b_w + (size_t)(r - 16) * HID);
      *(float4*)&ws[r][c4] = *(const float4*)&src[k0 + c4];
    }
    __syncthreads();
#pragma unroll 16
    for (int k = 0; k < 256; k += 4) {
      float4 a = *(const float4*)&xs[tl][k];
      float4 w0 = *(const float4*)&ws[n0][k];
      float4 w1 = *(const float4*)&ws[n0 + 16][k];
      acc0 += a.x * w0.x + a.y * w0.y + a.z * w0.z + a.w * w0.w;
      acc1 += a.x * w1.x + a.y * w1.y + a.z * w1.z + a.w * w1.w;
    }
    __syncthreads();
  }
  int m = m0 + tl, b = m >> 11, s = m & (S_LEN - 1);
  float z = acc0;
  float ls = (z >= 0.f) ? -log1pf(expf(-z)) : (z - log1pf(expf(z)));
  size_t oi = (size_t)(b * NH + n0) * S_LEN + s;
  al[oi] = expf(ls * 0.0625f);
  be[oi] = sigmoidf_(acc1);
}

// ---------------- causal dwconv(K=4)+SiLU, l2norm(q,k), q scale, qk_dot ----------------
__global__ __launch_bounds__(256) void conv_kernel(const float* __restrict__ qkv,
                                                   const float* __restrict__ conv_w,
                                                   float* __restrict__ qn,
                                                   float* __restrict__ kn,
                                                   float* __restrict__ vn,
                                                   float* __restrict__ qkd) {
  __shared__ float ys[QKV_DIM];
  __shared__ float sc[20];
  int m = blockIdx.x;
  int b = m >> 11, s = m & (S_LEN - 1);
  int tid = threadIdx.x;
  for (int c = tid; c < QKV_DIM; c += 256) {
    float acc = 0.f;
#pragma unroll
    for (int i = 0; i < 4; ++i) {
      int si = s - 3 + i;
      if (si >= 0) acc += conv_w[c * 4 + i] * qkv[(size_t)(b * S_LEN + si) * QKV_DIM + c];
    }
    ys[c] = acc * (1.f / (1.f + __expf(-acc)));  // SiLU
  }
  __syncthreads();
  int wv = tid >> 6, lane = tid & 63;
  for (int ch = wv; ch < 20; ch += 4) {
    int base = (ch < 16) ? ch * 128 : 2048 + (ch - 16) * 128;
    float x0 = ys[base + lane], x1 = ys[base + 64 + lane];
    float ss = x0 * x0 + x1 * x1;
#pragma unroll
    for (int off = 1; off < 64; off <<= 1) ss += __shfl_xor(ss, off);
    float scale = rsqrtf(ss + 1e-6f);
    if (ch < 16) scale *= 0.08838834764831845f;  // DK^-0.5
    if (lane == 0) sc[ch] = scale;
  }
  __syncthreads();
  for (int c = tid; c < 2048; c += 256) {
    int h = c >> 7, d = c & 127;
    qn[((size_t)(b * NH + h) * S_LEN + s) * DKQ + d] = ys[c] * sc[h];
  }
  for (int c = tid; c < 512; c += 256) {
    int j = c >> 7, d = c & 127;
    kn[((size_t)(b * NKV + j) * S_LEN + s) * DKQ + d] = ys[2048 + c] * sc[16 + j];
    vn[((size_t)(b * NKV + j) * S_LEN + s) * DVV + d] = ys[2560 + c];
  }
  __syncthreads();
  for (int h = wv; h < NH; h += 4) {
    int kvh = h >> 2;
    float sq = sc[h], sk = sc[16 + kvh];
    float q0 = ys[h * 128 + lane] * sq, q1 = ys[h * 128 + 64 + lane] * sq;
    float k0 = ys[2048 + kvh * 128 + lane] * sk, k1 = ys[2048 + kvh * 128 + 64 + lane] * sk;
    float dt = q0 * k0 + q1 * k1;
#pragma unroll
    for (int off = 1; off < 64; off <<= 1) dt += __shfl_xor(dt, off);
    if (lane == 0) qkd[(size_t)(b * NH + h) * S_LEN + s] = dt;
  }
}

// ---------------- gated delta-rule scan: column-parallel, 8 lanes/column ----------------
// wave = (bh, chunk of 8 dv columns); lane: g=lane&7 (16 dk each), cl=lane>>3 (column)
__global__ __launch_bounds__(256) void scan_kernel(const float* __restrict__ qn,
                                                   const float* __restrict__ kn,
                                                   const float* __restrict__ vn,
                                                   const float* __restrict__ al,
                                                   const float* __restrict__ be,
                                                   const float* __restrict__ qkd,
                                                   float* __restrict__ o_buf) {
  int wv = blockIdx.x * 4 + (threadIdx.x >> 6);  // 0..511
  int bh = wv >> 4;                              // 0..31
  int chunk = wv & 15;                           // 0..15
  int lane = threadIdx.x & 63;
  int g = lane & 7;
  int cl = lane >> 3;
  int dv = chunk * 8 + cl;
  int b = bh >> 4, h = bh & 15, kvh = h >> 2;
  const float* qrow = qn + (size_t)bh * S_LEN * DKQ + g * 16;
  const float* krow = kn + (size_t)(b * NKV + kvh) * S_LEN * DKQ + g * 16;
  const float* vrow = vn + (size_t)(b * NKV + kvh) * S_LEN * DVV + dv;
  const float* alr = al + (size_t)bh * S_LEN;
  const float* ber = be + (size_t)bh * S_LEN;
  const float* qkr = qkd + (size_t)bh * S_LEN;
  float* orow = o_buf + (size_t)bh * S_LEN * DVV + dv;

  float S[16];
#pragma unroll
  for (int i = 0; i < 16; ++i) S[i] = 0.f;

  float4 kx[4], qx[4];
#pragma unroll
  for (int i = 0; i < 4; ++i) {
    kx[i] = *(const float4*)(krow + i * 4);
    qx[i] = *(const float4*)(qrow + i * 4);
  }
  for (int t = 0; t < S_LEN; ++t) {
    float a = alr[t], bt = ber[t], qk = qkr[t];
    float vv = vrow[(size_t)t * DVV];
    int tn_ = (t + 1 < S_LEN) ? (t + 1) : t;  // prefetch next step's q/k fragments
    float4 nk[4], nq[4];
#pragma unroll
    for (int i = 0; i < 4; ++i) {
      nk[i] = *(const float4*)(krow + (size_t)tn_ * DKQ + i * 4);
      nq[i] = *(const float4*)(qrow + (size_t)tn_ * DKQ + i * 4);
    }
    const float* kk = (const float*)kx;
    const float* qq = (const float*)qx;
    float u0 = 0.f, u1 = 0.f, w0 = 0.f, w1 = 0.f;
#pragma unroll
    for (int i = 0; i < 16; i += 2) {
      u0 += kk[i] * S[i];     w0 += qq[i] * S[i];
      u1 += kk[i + 1] * S[i + 1]; w1 += qq[i + 1] * S[i + 1];
    }
    float u = u0 + u1, w = w0 + w1;
    u += __shfl_xor(u, 1); w += __shfl_xor(w, 1);
    u += __shfl_xor(u, 2); w += __shfl_xor(w, 2);
    u += __shfl_xor(u, 4); w += __shfl_xor(w, 4);
    float delta = (vv - a * u) * bt;
    float o = a * w + qk * delta;
#pragma unroll
    for (int i = 0; i < 16; ++i) S[i] = a * S[i] + kk[i] * delta;
    if (g == 0) orow[(size_t)t * DVV] = o;
#pragma unroll
    for (int i = 0; i < 4; ++i) { kx[i] = nk[i]; qx[i] = nq[i]; }
  }
}

// ---------------- per-head RMSNorm * out_norm_w * silu(g) -> og [M, H*DV] ----------------
__global__ __launch_bounds__(256) void normgate_kernel(const float* __restrict__ o_buf,
                                                       const float* __restrict__ g_buf,
                                                       const float* __restrict__ nw,
                                                       float* __restrict__ og) {
  int gid = blockIdx.x * 4 + (threadIdx.x >> 6);
  int lane = threadIdx.x & 63;
  int m = gid >> 4, h = gid & 15;
  int b = m >> 11, s = m & (S_LEN - 1);
  const float* orow = o_buf + ((size_t)(b * NH + h) * S_LEN + s) * DVV;
  float o0 = orow[lane], o1 = orow[lane + 64];
  float ss = o0 * o0 + o1 * o1;
#pragma unroll
  for (int off = 1; off < 64; off <<= 1) ss += __shfl_xor(ss, off);
  float r = rsqrtf(ss * (1.f / 128.f) + 1e-5f);
  size_t gi = (size_t)m * HID + h * DVV;
  float g0 = g_buf[gi + lane], g1 = g_buf[gi + lane + 64];
  og[gi + lane] = o0 * r * nw[lane] * (g0 * sigmoidf_(g0));
  og[gi + lane + 64] = o1 * r * nw[lane + 64] * (g1 * sigmoidf_(g1));
}

extern "C" void kernel_launch(void* const* d_in, const int* in_sizes, int n_in,
                              void* d_out, int out_size, void* d_ws, size_t ws_size,
                              hipStream_t stream) {
  const float* X      = (const float*)d_in[0];
  const float* qkv_w  = (const float*)d_in[1];
  const float* g_w    = (const float*)d_in[2];
  const float* b_w    = (const float*)d_in[3];
  const float* gk_w   = (const float*)d_in[4];
  const float* conv_w = (const float*)d_in[5];
  const float* norm_w = (const float*)d_in[6];
  const float* o_w    = (const float*)d_in[7];
  float* out = (float*)d_out;

  float* wsp = (float*)d_ws;
  float* qkv_buf = wsp;                                    // 4096*3072; reused as g_buf
  float* qn = qkv_buf + (size_t)M_TOK * QKV_DIM;           // 4096*2048; reused as og
  float* kn = qn + (size_t)M_TOK * HID;                    // 2*4*2048*128
  float* vn = kn + (size_t)BATCH * NKV * S_LEN * DKQ;      // 2*4*2048*128
  float* al = vn + (size_t)BATCH * NKV * S_LEN * DVV;      // 2*16*2048
  float* be = al + (size_t)BATCH * NH * S_LEN;
  float* qkd = be + (size_t)BATCH * NH * S_LEN;
  float* o_buf = qkd + (size_t)BATCH * NH * S_LEN;         // 2*16*2048*128
  float* g_buf = qkv_buf;
  float* og = qn;

  dim3 blk(256);
  // 1) qkv projection
  gemm_nt128<<<dim3(QKV_DIM / 128, M_TOK / 128), blk, 0, stream>>>(X, qkv_w, qkv_buf, M_TOK, QKV_DIM, HID);
  // 2) alpha/beta
  gkb_kernel<<<dim3(M_TOK / 16), blk, 0, stream>>>(X, gk_w, b_w, al, be);
  // 3) conv + silu + l2norm + qk_dot (consumes qkv_buf)
  conv_kernel<<<dim3(M_TOK), blk, 0, stream>>>(qkv_buf, conv_w, qn, kn, vn, qkd);
  // 4) g projection (overwrites qkv_buf; conv done)
  gemm_nt128<<<dim3(HID / 128, M_TOK / 128), blk, 0, stream>>>(X, g_w, g_buf, M_TOK, HID, HID);
  // 5) sequential gated delta scan
  scan_kernel<<<dim3(128), blk, 0, stream>>>(qn, kn, vn, al, be, qkd, o_buf);
  // 6) RMSNorm + gate (og overwrites qn; scan done)
  normgate_kernel<<<dim3(M_TOK * NH / 4), blk, 0, stream>>>(o_buf, g_buf, norm_w, og);
  // 7) output projection
  gemm_nt128<<<dim3(HID / 128, M_TOK / 128), blk, 0, stream>>>(og, o_w, out, M_TOK, HID, HID);
}

// Round 2
// 2335.326 us; speedup vs baseline: 1.4974x; 1.4974x over previous
//
#include <hip/hip_runtime.h>
#include <math.h>

#define S_LEN 2048
#define BATCH 2
#define NH 16
#define NKV 4
#define DKQ 128
#define DVV 128
#define HID 2048
#define QKV_DIM 3072
#define M_TOK 4096

#define T_TILE 32
#define CH_STRIDE 20           // 16 floats per chunk + 4 pad (16B-aligned, conflict-free)
#define ROW_F (8 * CH_STRIDE)  // 160 floats per staged row

__device__ __forceinline__ float sigmoidf_(float x) { return 1.f / (1.f + __expf(-x)); }

// ---------------- GEMM NT: C[M,N] = A[M,K] * B[N,K]^T (both K-contiguous) ----------------
__global__ __launch_bounds__(256) void gemm_nt128(const float* __restrict__ A,
                                                  const float* __restrict__ B,
                                                  float* __restrict__ C,
                                                  int M, int N, int K) {
  __shared__ float As[16][132];
  __shared__ float Bs[16][132];
  int bm = blockIdx.y * 128, bn = blockIdx.x * 128;
  int tid = threadIdx.x;
  int tm = tid >> 4, tn = tid & 15;
  float acc[8][8];
#pragma unroll
  for (int i = 0; i < 8; ++i)
#pragma unroll
    for (int j = 0; j < 8; ++j) acc[i][j] = 0.f;

  for (int k0 = 0; k0 < K; k0 += 16) {
#pragma unroll
    for (int i = 0; i < 2; ++i) {
      int F = tid + 256 * i;
      int r = F >> 2, kq = (F & 3) * 4;
      float4 av = *(const float4*)&A[(size_t)(bm + r) * K + k0 + kq];
      float4 bv = *(const float4*)&B[(size_t)(bn + r) * K + k0 + kq];
      As[kq + 0][r] = av.x; As[kq + 1][r] = av.y; As[kq + 2][r] = av.z; As[kq + 3][r] = av.w;
      Bs[kq + 0][r] = bv.x; Bs[kq + 1][r] = bv.y; Bs[kq + 2][r] = bv.z; Bs[kq + 3][r] = bv.w;
    }
    __syncthreads();
#pragma unroll
    for (int kk = 0; kk < 16; ++kk) {
      float a[8], b[8];
      *(float4*)&a[0] = *(const float4*)&As[kk][tm * 4];
      *(float4*)&a[4] = *(const float4*)&As[kk][64 + tm * 4];
      *(float4*)&b[0] = *(const float4*)&Bs[kk][tn * 4];
      *(float4*)&b[4] = *(const float4*)&Bs[kk][64 + tn * 4];
#pragma unroll
      for (int i = 0; i < 8; ++i)
#pragma unroll
        for (int j = 0; j < 8; ++j) acc[i][j] += a[i] * b[j];
    }
    __syncthreads();
  }
#pragma unroll
  for (int i = 0; i < 8; ++i) {
    int m = bm + (i < 4 ? tm * 4 + i : 64 + tm * 4 + (i - 4));
#pragma unroll
    for (int jh = 0; jh < 2; ++jh) {
      int n = bn + jh * 64 + tn * 4;
      float4 v = make_float4(acc[i][jh * 4 + 0], acc[i][jh * 4 + 1],
                             acc[i][jh * 4 + 2], acc[i][jh * 4 + 3]);
      *(float4*)&C[(size_t)m * N + n] = v;
    }
  }
}

// ---------------- gk/b projections -> alpha [B,H,S], beta [B,H,S] ----------------
__global__ __launch_bounds__(256) void gkb_kernel(const float* __restrict__ X,
                                                  const float* __restrict__ gk_w,
                                                  const float* __restrict__ b_w,
                                                  float* __restrict__ al,
                                                  float* __restrict__ be) {
  __shared__ float xs[16][260];
  __shared__ float ws[32][260];
  int tid = threadIdx.x;
  int m0 = blockIdx.x * 16;
  int tl = tid >> 4, n0 = tid & 15;
  float acc0 = 0.f, acc1 = 0.f;
  for (int k0 = 0; k0 < HID; k0 += 256) {
#pragma unroll
    for (int i = 0; i < 4; ++i) {
      int F = i * 256 + tid;
      int r = F >> 6, c4 = (F & 63) * 4;
      *(float4*)&xs[r][c4] = *(const float4*)&X[(size_t)(m0 + r) * HID + k0 + c4];
    }
#pragma unroll
    for (int i = 0; i < 8; ++i) {
      int F = i * 256 + tid;
      int r = F >> 6, c4 = (F & 63) * 4;
      const float* src = (r < 16) ? (gk_w + (size_t)r * HID) : (b_w + (size_t)(r - 16) * HID);
      *(float4*)&ws[r][c4] = *(const float4*)&src[k0 + c4];
    }
    __syncthreads();
#pragma unroll 16
    for (int k = 0; k < 256; k += 4) {
      float4 a = *(const float4*)&xs[tl][k];
      float4 w0 = *(const float4*)&ws[n0][k];
      float4 w1 = *(const float4*)&ws[n0 + 16][k];
      acc0 += a.x * w0.x + a.y * w0.y + a.z * w0.z + a.w * w0.w;
      acc1 += a.x * w1.x + a.y * w1.y + a.z * w1.z + a.w * w1.w;
    }
    __syncthreads();
  }
  int m = m0 + tl, b = m >> 11, s = m & (S_LEN - 1);
  float z = acc0;
  float ls = (z >= 0.f) ? -log1pf(expf(-z)) : (z - log1pf(expf(z)));
  size_t oi = (size_t)(b * NH + n0) * S_LEN + s;
  al[oi] = expf(ls * 0.0625f);
  be[oi] = sigmoidf_(acc1);
}

// ---------------- causal dwconv(K=4)+SiLU, l2norm(q,k), q scale, qk_dot ----------------
__global__ __launch_bounds__(256) void conv_kernel(const float* __restrict__ qkv,
                                                   const float* __restrict__ conv_w,
                                                   float* __restrict__ qn,
                                                   float* __restrict__ kn,
                                                   float* __restrict__ vn,
                                                   float* __restrict__ qkd) {
  __shared__ float ys[QKV_DIM];
  __shared__ float sc[20];
  int m = blockIdx.x;
  int b = m >> 11, s = m & (S_LEN - 1);
  int tid = threadIdx.x;
  for (int c = tid; c < QKV_DIM; c += 256) {
    float acc = 0.f;
#pragma unroll
    for (int i = 0; i < 4; ++i) {
      int si = s - 3 + i;
      if (si >= 0) acc += conv_w[c * 4 + i] * qkv[(size_t)(b * S_LEN + si) * QKV_DIM + c];
    }
    ys[c] = acc * (1.f / (1.f + __expf(-acc)));  // SiLU
  }
  __syncthreads();
  int wv = tid >> 6, lane = tid & 63;
  for (int ch = wv; ch < 20; ch += 4) {
    int base = (ch < 16) ? ch * 128 : 2048 + (ch - 16) * 128;
    float x0 = ys[base + lane], x1 = ys[base + 64 + lane];
    float ss = x0 * x0 + x1 * x1;
#pragma unroll
    for (int off = 1; off < 64; off <<= 1) ss += __shfl_xor(ss, off);
    float scale = rsqrtf(ss + 1e-6f);
    if (ch < 16) scale *= 0.08838834764831845f;  // DK^-0.5
    if (lane == 0) sc[ch] = scale;
  }
  __syncthreads();
  for (int c = tid; c < 2048; c += 256) {
    int h = c >> 7, d = c & 127;
    qn[((size_t)(b * NH + h) * S_LEN + s) * DKQ + d] = ys[c] * sc[h];
  }
  for (int c = tid; c < 512; c += 256) {
    int j = c >> 7, d = c & 127;
    kn[((size_t)(b * NKV + j) * S_LEN + s) * DKQ + d] = ys[2048 + c] * sc[16 + j];
    vn[((size_t)(b * NKV + j) * S_LEN + s) * DVV + d] = ys[2560 + c];
  }
  __syncthreads();
  for (int h = wv; h < NH; h += 4) {
    int kvh = h >> 2;
    float sq = sc[h], sk = sc[16 + kvh];
    float q0 = ys[h * 128 + lane] * sq, q1 = ys[h * 128 + 64 + lane] * sq;
    float k0 = ys[2048 + kvh * 128 + lane] * sk, k1 = ys[2048 + kvh * 128 + 64 + lane] * sk;
    float dt = q0 * k0 + q1 * k1;
#pragma unroll
    for (int off = 1; off < 64; off <<= 1) dt += __shfl_xor(dt, off);
    if (lane == 0) qkd[(size_t)(b * NH + h) * S_LEN + s] = dt;
  }
}

// ---------------- gated delta-rule scan: LDS-tiled, double-buffered ----------------
// grid 256: block = (bh, group of 16 dv cols); 128 threads = 2 waves.
// lane: g = lane&7 (16 dk each), cl = lane>>3 (col within wave); col = colgrp*16 + wid*8 + cl.
__global__ __launch_bounds__(128) void scan_kernel(const float* __restrict__ qn,
                                                   const float* __restrict__ kn,
                                                   const float* __restrict__ vn,
                                                   const float* __restrict__ al,
                                                   const float* __restrict__ be,
                                                   const float* __restrict__ qkd,
                                                   float* __restrict__ o_buf) {
  __shared__ float lq[2][T_TILE][ROW_F];
  __shared__ float lk[2][T_TILE][ROW_F];
  __shared__ float lv[2][T_TILE][16];
  __shared__ float lsc[2][3][T_TILE];

  int blk = blockIdx.x;    // 256
  int bh = blk >> 3;       // 0..31
  int colgrp = blk & 7;    // 0..7
  int tid = threadIdx.x;   // 0..127
  int wid = tid >> 6;
  int lane = tid & 63;
  int g = lane & 7;
  int cl = lane >> 3;
  int colLocal = wid * 8 + cl;  // 0..15
  int col = colgrp * 16 + colLocal;
  int b = bh >> 4, h = bh & 15, kvh = h >> 2;

  const float* qbase = qn + (size_t)bh * S_LEN * DKQ;
  const float* kbase = kn + (size_t)(b * NKV + kvh) * S_LEN * DKQ;
  const float* vbase = vn + (size_t)(b * NKV + kvh) * S_LEN * DVV;
  const float* alr = al + (size_t)bh * S_LEN;
  const float* ber = be + (size_t)bh * S_LEN;
  const float* qkr = qkd + (size_t)bh * S_LEN;
  float* orow = o_buf + (size_t)bh * S_LEN * DVV;

  // precomputed staging indices
  int st_t = tid >> 2, st_cs = tid & 3;        // v staging: t, col-seg
  int sc_which = tid >> 5, sc_tt = tid & 31;   // scalar staging

  float S[16];
#pragma unroll
  for (int i = 0; i < 16; ++i) S[i] = 0.f;

  // ---- stage tile 0 into buffer 0 ----
#pragma unroll
  for (int j = 0; j < 8; ++j) {
    int idx = j * 128 + tid;             // float4 index within 32x128 tile
    int t = idx >> 5;
    int d = (idx & 31) * 4;
    int ch = d >> 4, off = d & 15;
    float4 vq = *(const float4*)&qbase[(size_t)t * DKQ + d];
    float4 vk = *(const float4*)&kbase[(size_t)t * DKQ + d];
    *(float4*)&lq[0][t][ch * CH_STRIDE + off] = vq;
    *(float4*)&lk[0][t][ch * CH_STRIDE + off] = vk;
  }
  *(float4*)&lv[0][st_t][st_cs * 4] =
      *(const float4*)&vbase[(size_t)st_t * DVV + colgrp * 16 + st_cs * 4];
  if (tid < 96) {
    const float* p = (sc_which == 0) ? alr : (sc_which == 1) ? ber : qkr;
    lsc[0][sc_which][sc_tt] = p[sc_tt];
  }
  __syncthreads();

  for (int tile = 0; tile < S_LEN / T_TILE; ++tile) {
    int cur = tile & 1;
    bool have = (tile + 1 < S_LEN / T_TILE);
    int t0n = (tile + 1) * T_TILE;

    // ---- issue next tile's global loads into registers (in flight over compute) ----
    float4 rq[8], rk[8], rv;
    float rsc = 0.f;
    if (have) {
#pragma unroll
      for (int j = 0; j < 8; ++j) {
        int idx = j * 128 + tid;
        int t = idx >> 5;
        int d = (idx & 31) * 4;
        rq[j] = *(const float4*)&qbase[(size_t)(t0n + t) * DKQ + d];
        rk[j] = *(const float4*)&kbase[(size_t)(t0n + t) * DKQ + d];
      }
      rv = *(const float4*)&vbase[(size_t)(t0n + st_t) * DVV + colgrp * 16 + st_cs * 4];
      if (tid < 96) {
        const float* p = (sc_which == 0) ? alr : (sc_which == 1) ? ber : qkr;
        rsc = p[t0n + sc_tt];
      }
    }

    // ---- compute T_TILE steps from buffer `cur` ----
    float4 kx[4], qx[4];
#pragma unroll
    for (int i = 0; i < 4; ++i) {
      kx[i] = *(const float4*)&lk[cur][0][g * CH_STRIDE + i * 4];
      qx[i] = *(const float4*)&lq[cur][0][g * CH_STRIDE + i * 4];
    }
    int tglob0 = tile * T_TILE;
#pragma unroll 4
    for (int t = 0; t < T_TILE; ++t) {
      float a = lsc[cur][0][t], bt = lsc[cur][1][t], qk = lsc[cur][2][t];
      float vv = lv[cur][t][colLocal];
      int tn_ = (t + 1 < T_TILE) ? (t + 1) : t;
      float4 nk[4], nq[4];
#pragma unroll
      for (int i = 0; i < 4; ++i) {
        nk[i] = *(const float4*)&lk[cur][tn_][g * CH_STRIDE + i * 4];
        nq[i] = *(const float4*)&lq[cur][tn_][g * CH_STRIDE + i * 4];
      }
      const float* kk = (const float*)kx;
      const float* qq = (const float*)qx;
      float u0 = 0.f, u1 = 0.f, w0 = 0.f, w1 = 0.f;
#pragma unroll
      for (int i = 0; i < 16; i += 2) {
        u0 += kk[i] * S[i];         w0 += qq[i] * S[i];
        u1 += kk[i + 1] * S[i + 1]; w1 += qq[i + 1] * S[i + 1];
      }
      float u = u0 + u1, w = w0 + w1;
      u += __shfl_xor(u, 1); w += __shfl_xor(w, 1);
      u += __shfl_xor(u, 2); w += __shfl_xor(w, 2);
      u += __shfl_xor(u, 4); w += __shfl_xor(w, 4);
      float delta = (vv - a * u) * bt;
      float o = a * w + qk * delta;
#pragma unroll
      for (int i = 0; i < 16; ++i) S[i] = a * S[i] + kk[i] * delta;
      if (g == 0) orow[(size_t)(tglob0 + t) * DVV + col] = o;
#pragma unroll
      for (int i = 0; i < 4; ++i) { kx[i] = nk[i]; qx[i] = nq[i]; }
    }

    // ---- write staged registers into the other buffer ----
    if (have) {
      int nb = 1 - cur;
#pragma unroll
      for (int j = 0; j < 8; ++j) {
        int idx = j * 128 + tid;
        int t = idx >> 5;
        int d = (idx & 31) * 4;
        int ch = d >> 4, off = d & 15;
        *(float4*)&lq[nb][t][ch * CH_STRIDE + off] = rq[j];
        *(float4*)&lk[nb][t][ch * CH_STRIDE + off] = rk[j];
      }
      *(float4*)&lv[nb][st_t][st_cs * 4] = rv;
      if (tid < 96) lsc[nb][sc_which][sc_tt] = rsc;
    }
    __syncthreads();
  }
}

// ---------------- per-head RMSNorm * out_norm_w * silu(g) -> og [M, H*DV] ----------------
__global__ __launch_bounds__(256) void normgate_kernel(const float* __restrict__ o_buf,
                                                       const float* __restrict__ g_buf,
                                                       const float* __restrict__ nw,
                                                       float* __restrict__ og) {
  int gid = blockIdx.x * 4 + (threadIdx.x >> 6);
  int lane = threadIdx.x & 63;
  int m = gid >> 4, h = gid & 15;
  int b = m >> 11, s = m & (S_LEN - 1);
  const float* orow = o_buf + ((size_t)(b * NH + h) * S_LEN + s) * DVV;
  float o0 = orow[lane], o1 = orow[lane + 64];
  float ss = o0 * o0 + o1 * o1;
#pragma unroll
  for (int off = 1; off < 64; off <<= 1) ss += __shfl_xor(ss, off);
  float r = rsqrtf(ss * (1.f / 128.f) + 1e-5f);
  size_t gi = (size_t)m * HID + h * DVV;
  float g0 = g_buf[gi + lane], g1 = g_buf[gi + lane + 64];
  og[gi + lane] = o0 * r * nw[lane] * (g0 * sigmoidf_(g0));
  og[gi + lane + 64] = o1 * r * nw[lane + 64] * (g1 * sigmoidf_(g1));
}

extern "C" void kernel_launch(void* const* d_in, const int* in_sizes, int n_in,
                              void* d_out, int out_size, void* d_ws, size_t ws_size,
                              hipStream_t stream) {
  const float* X      = (const float*)d_in[0];
  const float* qkv_w  = (const float*)d_in[1];
  const float* g_w    = (const float*)d_in[2];
  const float* b_w    = (const float*)d_in[3];
  const float* gk_w   = (const float*)d_in[4];
  const float* conv_w = (const float*)d_in[5];
  const float* norm_w = (const float*)d_in[6];
  const float* o_w    = (const float*)d_in[7];
  float* out = (float*)d_out;

  float* wsp = (float*)d_ws;
  float* qkv_buf = wsp;                                    // 4096*3072; reused as g_buf
  float* qn = qkv_buf + (size_t)M_TOK * QKV_DIM;           // 4096*2048; reused as og
  float* kn = qn + (size_t)M_TOK * HID;                    // 2*4*2048*128
  float* vn = kn + (size_t)BATCH * NKV * S_LEN * DKQ;      // 2*4*2048*128
  float* al = vn + (size_t)BATCH * NKV * S_LEN * DVV;      // 2*16*2048
  float* be = al + (size_t)BATCH * NH * S_LEN;
  float* qkd = be + (size_t)BATCH * NH * S_LEN;
  float* o_buf = qkd + (size_t)BATCH * NH * S_LEN;         // 2*16*2048*128
  float* g_buf = qkv_buf;
  float* og = qn;

  dim3 blk(256);
  // 1) qkv projection
  gemm_nt128<<<dim3(QKV_DIM / 128, M_TOK / 128), blk, 0, stream>>>(X, qkv_w, qkv_buf, M_TOK, QKV_DIM, HID);
  // 2) alpha/beta
  gkb_kernel<<<dim3(M_TOK / 16), blk, 0, stream>>>(X, gk_w, b_w, al, be);
  // 3) conv + silu + l2norm + qk_dot (consumes qkv_buf)
  conv_kernel<<<dim3(M_TOK), blk, 0, stream>>>(qkv_buf, conv_w, qn, kn, vn, qkd);
  // 4) g projection (overwrites qkv_buf; conv done)
  gemm_nt128<<<dim3(HID / 128, M_TOK / 128), blk, 0, stream>>>(X, g_w, g_buf, M_TOK, HID, HID);
  // 5) sequential gated delta scan (LDS-tiled, double-buffered)
  scan_kernel<<<dim3(256), dim3(128), 0, stream>>>(qn, kn, vn, al, be, qkd, o_buf);
  // 6) RMSNorm + gate (og overwrites qn; scan done)
  normgate_kernel<<<dim3(M_TOK * NH / 4), blk, 0, stream>>>(o_buf, g_buf, norm_w, og);
  // 7) output projection
  gemm_nt128<<<dim3(HID / 128, M_TOK / 128), blk, 0, stream>>>(og, o_w, out, M_TOK, HID, HID);
}

// Round 3
// 1262.467 us; speedup vs baseline: 2.7698x; 1.8498x over previous
//
#include <hip/hip_runtime.h>
#include <math.h>

#define S_LEN 2048
#define BATCH 2
#define NH 16
#define NKV 4
#define DKQ 128
#define DVV 128
#define HID 2048
#define QKV_DIM 3072
#define M_TOK 4096

typedef _Float16 halfx8 __attribute__((ext_vector_type(8)));
typedef float floatx4 __attribute__((ext_vector_type(4)));

#define AS1 __attribute__((address_space(1)))
#define AS3 __attribute__((address_space(3)))
#define GLD16(gp, lp) __builtin_amdgcn_global_load_lds((AS1 const void*)(gp), (AS3 void*)(lp), 16, 0, 0)

__device__ __forceinline__ float sigmoidf_(float x) { return 1.f / (1.f + __expf(-x)); }

// ---------------- f32 -> f16 convert (8 elems/thread) ----------------
__global__ __launch_bounds__(256) void cvt_f16(const float* __restrict__ in,
                                               _Float16* __restrict__ out, int n8) {
  int i = blockIdx.x * 256 + threadIdx.x;
  if (i >= n8) return;
  const float4* p = (const float4*)in;
  float4 a = p[2 * (size_t)i], b = p[2 * (size_t)i + 1];
  halfx8 o;
  o[0] = (_Float16)a.x; o[1] = (_Float16)a.y; o[2] = (_Float16)a.z; o[3] = (_Float16)a.w;
  o[4] = (_Float16)b.x; o[5] = (_Float16)b.y; o[6] = (_Float16)b.z; o[7] = (_Float16)b.w;
  *(halfx8*)(out + (size_t)i * 8) = o;
}

// ---------------- fp16 MFMA GEMM NT: C[M,N] f32 = A[M,K] * B[N,K]^T ----------------
// 128x128 tile, 256 thr = 4 waves, each wave 64x64 (4x4 of 16x16x32 frags), BK=32.
// Staging via global_load_lds width=16 (wave-uniform LDS base + lane*16).
__global__ __launch_bounds__(256) void gemm_bt_f16(const _Float16* __restrict__ A,
                                                   const _Float16* __restrict__ B,
                                                   float* __restrict__ C,
                                                   int M, int N, int K) {
  __shared__ _Float16 As[128 * 32];
  __shared__ _Float16 Bs[128 * 32];
  int bm = blockIdx.y * 128, bn = blockIdx.x * 128;
  int tid = threadIdx.x;
  int w = tid >> 6, l = tid & 63;
  int wm = (w & 1) * 64, wn = (w >> 1) * 64;
  int lrow = l & 15, lk8 = (l >> 4) * 8;

  floatx4 zero = {0.f, 0.f, 0.f, 0.f};
  floatx4 acc[4][4];
#pragma unroll
  for (int i = 0; i < 4; ++i)
#pragma unroll
    for (int j = 0; j < 4; ++j) acc[i][j] = zero;

  const _Float16* ga = A + (size_t)(bm + (tid >> 2)) * K + (tid & 3) * 8;
  const _Float16* gb = B + (size_t)(bn + (tid >> 2)) * K + (tid & 3) * 8;
  _Float16* lA = As + w * 512;  // wave-uniform base: lane writes base + lane*16B
  _Float16* lB = Bs + w * 512;

  for (int k0 = 0; k0 < K; k0 += 32) {
    GLD16(ga + k0, lA);
    GLD16(ga + k0 + (size_t)64 * K, lA + 2048);
    GLD16(gb + k0, lB);
    GLD16(gb + k0 + (size_t)64 * K, lB + 2048);
    __syncthreads();  // drains vmcnt(0): staged data visible
    halfx8 af[4], bf_[4];
#pragma unroll
    for (int mi = 0; mi < 4; ++mi)
      af[mi] = *(const halfx8*)&As[(wm + mi * 16 + lrow) * 32 + lk8];
#pragma unroll
    for (int ni = 0; ni < 4; ++ni)
      bf_[ni] = *(const halfx8*)&Bs[(wn + ni * 16 + lrow) * 32 + lk8];
#pragma unroll
    for (int mi = 0; mi < 4; ++mi)
#pragma unroll
      for (int ni = 0; ni < 4; ++ni)
        acc[mi][ni] = __builtin_amdgcn_mfma_f32_16x16x32_f16(af[mi], bf_[ni], acc[mi][ni], 0, 0, 0);
    __syncthreads();
  }
  // C/D layout: col = lane&15, row = (lane>>4)*4 + reg
  int r0 = (l >> 4) * 4;
#pragma unroll
  for (int mi = 0; mi < 4; ++mi)
#pragma unroll
    for (int ni = 0; ni < 4; ++ni) {
      int col = bn + wn + ni * 16 + lrow;
#pragma unroll
      for (int r = 0; r < 4; ++r)
        C[(size_t)(bm + wm + mi * 16 + r0 + r) * N + col] = acc[mi][ni][r];
    }
}

// ---------------- gk/b projections -> alpha [B,H,S], beta [B,H,S] (fp32) ----------------
__global__ __launch_bounds__(256) void gkb_kernel(const float* __restrict__ X,
                                                  const float* __restrict__ gk_w,
                                                  const float* __restrict__ b_w,
                                                  float* __restrict__ al,
                                                  float* __restrict__ be) {
  __shared__ float xs[16][260];
  __shared__ float ws[32][260];
  int tid = threadIdx.x;
  int m0 = blockIdx.x * 16;
  int tl = tid >> 4, n0 = tid & 15;
  float acc0 = 0.f, acc1 = 0.f;
  for (int k0 = 0; k0 < HID; k0 += 256) {
#pragma unroll
    for (int i = 0; i < 4; ++i) {
      int F = i * 256 + tid;
      int r = F >> 6, c4 = (F & 63) * 4;
      *(float4*)&xs[r][c4] = *(const float4*)&X[(size_t)(m0 + r) * HID + k0 + c4];
    }
#pragma unroll
    for (int i = 0; i < 8; ++i) {
      int F = i * 256 + tid;
      int r = F >> 6, c4 = (F & 63) * 4;
      const float* src = (r < 16) ? (gk_w + (size_t)r * HID) : (b_w + (size_t)(r - 16) * HID);
      *(float4*)&ws[r][c4] = *(const float4*)&src[k0 + c4];
    }
    __syncthreads();
#pragma unroll 16
    for (int k = 0; k < 256; k += 4) {
      float4 a = *(const float4*)&xs[tl][k];
      float4 w0 = *(const float4*)&ws[n0][k];
      float4 w1 = *(const float4*)&ws[n0 + 16][k];
      acc0 += a.x * w0.x + a.y * w0.y + a.z * w0.z + a.w * w0.w;
      acc1 += a.x * w1.x + a.y * w1.y + a.z * w1.z + a.w * w1.w;
    }
    __syncthreads();
  }
  int m = m0 + tl, b = m >> 11, s = m & (S_LEN - 1);
  float z = acc0;
  float ls = (z >= 0.f) ? -log1pf(expf(-z)) : (z - log1pf(expf(z)));
  size_t oi = (size_t)(b * NH + n0) * S_LEN + s;
  al[oi] = expf(ls * 0.0625f);
  be[oi] = sigmoidf_(acc1);
}

// ---------------- causal dwconv(K=4)+SiLU, l2norm(q,k), q scale, qk_dot ----------------
__global__ __launch_bounds__(256) void conv_kernel(const float* __restrict__ qkv,
                                                   const float* __restrict__ conv_w,
                                                   float* __restrict__ qn,
                                                   float* __restrict__ kn,
                                                   float* __restrict__ vn,
                                                   float* __restrict__ qkd) {
  __shared__ float ys[QKV_DIM];
  __shared__ float sc[20];
  int m = blockIdx.x;
  int b = m >> 11, s = m & (S_LEN - 1);
  int tid = threadIdx.x;
  for (int c = tid; c < QKV_DIM; c += 256) {
    float acc = 0.f;
#pragma unroll
    for (int i = 0; i < 4; ++i) {
      int si = s - 3 + i;
      if (si >= 0) acc += conv_w[c * 4 + i] * qkv[(size_t)(b * S_LEN + si) * QKV_DIM + c];
    }
    ys[c] = acc * (1.f / (1.f + __expf(-acc)));  // SiLU
  }
  __syncthreads();
  int wv = tid >> 6, lane = tid & 63;
  for (int ch = wv; ch < 20; ch += 4) {
    int base = (ch < 16) ? ch * 128 : 2048 + (ch - 16) * 128;
    float x0 = ys[base + lane], x1 = ys[base + 64 + lane];
    float ss = x0 * x0 + x1 * x1;
#pragma unroll
    for (int off = 1; off < 64; off <<= 1) ss += __shfl_xor(ss, off);
    float scale = rsqrtf(ss + 1e-6f);
    if (ch < 16) scale *= 0.08838834764831845f;  // DK^-0.5
    if (lane == 0) sc[ch] = scale;
  }
  __syncthreads();
  for (int c = tid; c < 2048; c += 256) {
    int h = c >> 7, d = c & 127;
    qn[((size_t)(b * NH + h) * S_LEN + s) * DKQ + d] = ys[c] * sc[h];
  }
  for (int c = tid; c < 512; c += 256) {
    int j = c >> 7, d = c & 127;
    kn[((size_t)(b * NKV + j) * S_LEN + s) * DKQ + d] = ys[2048 + c] * sc[16 + j];
    vn[((size_t)(b * NKV + j) * S_LEN + s) * DVV + d] = ys[2560 + c];
  }
  __syncthreads();
  for (int h = wv; h < NH; h += 4) {
    int kvh = h >> 2;
    float sq = sc[h], sk = sc[16 + kvh];
    float q0 = ys[h * 128 + lane] * sq, q1 = ys[h * 128 + 64 + lane] * sq;
    float k0 = ys[2048 + kvh * 128 + lane] * sk, k1 = ys[2048 + kvh * 128 + 64 + lane] * sk;
    float dt = q0 * k0 + q1 * k1;
#pragma unroll
    for (int off = 1; off < 64; off <<= 1) dt += __shfl_xor(dt, off);
    if (lane == 0) qkd[(size_t)(b * NH + h) * S_LEN + s] = dt;
  }
}

// ---------------- gated delta-rule scan ----------------
// 512 blocks x 64 thr (1 wave): block = (bh, 8 dv cols). lane: g=lane&7 (16 dk), cl=lane>>3.
// T=16 double-buffered LDS, zero barriers (single wave), o staged in LDS, coalesced flush.
__global__ __launch_bounds__(64) void scan_kernel(const float* __restrict__ qn,
                                                  const float* __restrict__ kn,
                                                  const float* __restrict__ vn,
                                                  const float* __restrict__ al,
                                                  const float* __restrict__ be,
                                                  const float* __restrict__ qkd,
                                                  float* __restrict__ o_buf) {
  __shared__ float lq[2][16][160];   // 8 chunks * (16+4 pad) per row
  __shared__ float lk[2][16][160];
  __shared__ float lv[2][16][8];
  __shared__ float lsc[2][3][16];
  __shared__ float lo[16][8];

  int blk = blockIdx.x;
  int bh = blk >> 4;
  int colgrp = blk & 15;
  int tid = threadIdx.x;
  int g = tid & 7, cl = tid >> 3;
  int b = bh >> 4, h = bh & 15, kvh = h >> 2;

  const float* qbase = qn + (size_t)bh * S_LEN * DKQ;
  const float* kbase = kn + (size_t)(b * NKV + kvh) * S_LEN * DKQ;
  const float* vbase = vn + (size_t)(b * NKV + kvh) * S_LEN * DVV + colgrp * 8;
  const float* alr = al + (size_t)bh * S_LEN;
  const float* ber = be + (size_t)bh * S_LEN;
  const float* qkr = qkd + (size_t)bh * S_LEN;
  float* orow = o_buf + (size_t)bh * S_LEN * DVV + colgrp * 8;

  int vt = tid >> 1, vs = (tid & 1) * 4;  // tid<32: v staging
  int scw = tid >> 4, sct = tid & 15;     // tid<48: scalar staging

  float S[16];
#pragma unroll
  for (int i = 0; i < 16; ++i) S[i] = 0.f;

  float4 rq[8], rk[8], rv = {0, 0, 0, 0};
  float rsc = 0.f;
#pragma unroll
  for (int j = 0; j < 8; ++j) {
    int idx = j * 64 + tid, t = idx >> 5, d = (idx & 31) * 4;
    rq[j] = *(const float4*)&qbase[(size_t)t * DKQ + d];
    rk[j] = *(const float4*)&kbase[(size_t)t * DKQ + d];
  }
  if (tid < 32) rv = *(const float4*)&vbase[(size_t)vt * DVV + vs];
  if (tid < 48) rsc = (scw == 0 ? alr : scw == 1 ? ber : qkr)[sct];
#pragma unroll
  for (int j = 0; j < 8; ++j) {
    int idx = j * 64 + tid, t = idx >> 5, d = (idx & 31) * 4, ch = d >> 4, off = d & 15;
    *(float4*)&lq[0][t][ch * 20 + off] = rq[j];
    *(float4*)&lk[0][t][ch * 20 + off] = rk[j];
  }
  if (tid < 32) *(float4*)&lv[0][vt][vs] = rv;
  if (tid < 48) lsc[0][scw][sct] = rsc;

  for (int tile = 0; tile < S_LEN / 16; ++tile) {
    int cur = tile & 1, nb = cur ^ 1;
    bool have = (tile + 1) < S_LEN / 16;
    int t0n = (tile + 1) * 16;
    if (have) {  // issue next tile's global loads (in flight across this tile's compute)
#pragma unroll
      for (int j = 0; j < 8; ++j) {
        int idx = j * 64 + tid, t = idx >> 5, d = (idx & 31) * 4;
        rq[j] = *(const float4*)&qbase[(size_t)(t0n + t) * DKQ + d];
        rk[j] = *(const float4*)&kbase[(size_t)(t0n + t) * DKQ + d];
      }
      if (tid < 32) rv = *(const float4*)&vbase[(size_t)(t0n + vt) * DVV + vs];
      if (tid < 48) rsc = (scw == 0 ? alr : scw == 1 ? ber : qkr)[t0n + sct];
    }
    // prime step 0
    float4 kx[4], qx[4];
#pragma unroll
    for (int i = 0; i < 4; ++i) {
      kx[i] = *(const float4*)&lk[cur][0][g * 20 + i * 4];
      qx[i] = *(const float4*)&lq[cur][0][g * 20 + i * 4];
    }
    float a_c = lsc[cur][0][0], b_c = lsc[cur][1][0], qk_c = lsc[cur][2][0], vv_c = lv[cur][0][cl];
    int tg0 = tile * 16;
#pragma unroll 4
    for (int t = 0; t < 16; ++t) {
      int tn = (t + 1 < 16) ? t + 1 : t;
      float a_n = lsc[cur][0][tn], b_n = lsc[cur][1][tn], qk_n = lsc[cur][2][tn];
      float vv_n = lv[cur][tn][cl];
      float4 nk[4], nq[4];
#pragma unroll
      for (int i = 0; i < 4; ++i) {
        nk[i] = *(const float4*)&lk[cur][tn][g * 20 + i * 4];
        nq[i] = *(const float4*)&lq[cur][tn][g * 20 + i * 4];
      }
      const float* kk = (const float*)kx;
      const float* qq = (const float*)qx;
      float u0 = 0, u1 = 0, u2 = 0, u3 = 0, w0 = 0, w1 = 0, w2 = 0, w3 = 0;
#pragma unroll
      for (int i = 0; i < 16; i += 4) {
        u0 += kk[i] * S[i];         w0 += qq[i] * S[i];
        u1 += kk[i + 1] * S[i + 1]; w1 += qq[i + 1] * S[i + 1];
        u2 += kk[i + 2] * S[i + 2]; w2 += qq[i + 2] * S[i + 2];
        u3 += kk[i + 3] * S[i + 3]; w3 += qq[i + 3] * S[i + 3];
      }
      float u = (u0 + u1) + (u2 + u3), w = (w0 + w1) + (w2 + w3);
      u += __shfl_xor(u, 1); w += __shfl_xor(w, 1);
      u += __shfl_xor(u, 2); w += __shfl_xor(w, 2);
      u += __shfl_xor(u, 4); w += __shfl_xor(w, 4);
      float delta = (vv_c - a_c * u) * b_c;
      float o = a_c * w + qk_c * delta;
#pragma unroll
      for (int i = 0; i < 16; ++i) S[i] = a_c * S[i] + kk[i] * delta;
      if (g == 0) lo[t][cl] = o;
      a_c = a_n; b_c = b_n; qk_c = qk_n; vv_c = vv_n;
#pragma unroll
      for (int i = 0; i < 4; ++i) { kx[i] = nk[i]; qx[i] = nq[i]; }
    }
    // flush o tile (single wave => no barrier; compiler orders LDS deps)
    {
      int t = tid >> 2, c2 = (tid & 3) * 2;
      float2 ov = *(float2*)&lo[t][c2];
      *(float2*)&orow[(size_t)(tg0 + t) * DVV + c2] = ov;
    }
    if (have) {  // write staged regs into other buffer
#pragma unroll
      for (int j = 0; j < 8; ++j) {
        int idx = j * 64 + tid, t = idx >> 5, d = (idx & 31) * 4, ch = d >> 4, off = d & 15;
        *(float4*)&lq[nb][t][ch * 20 + off] = rq[j];
        *(float4*)&lk[nb][t][ch * 20 + off] = rk[j];
      }
      if (tid < 32) *(float4*)&lv[nb][vt][vs] = rv;
      if (tid < 48) lsc[nb][scw][sct] = rsc;
    }
  }
}

// ---------------- per-head RMSNorm * out_norm_w * silu(g) -> og fp16 [M, H*DV] ----------------
__global__ __launch_bounds__(256) void normgate_kernel(const float* __restrict__ o_buf,
                                                       const float* __restrict__ g_buf,
                                                       const float* __restrict__ nw,
                                                       _Float16* __restrict__ og) {
  int gid = blockIdx.x * 4 + (threadIdx.x >> 6);
  int lane = threadIdx.x & 63;
  int m = gid >> 4, h = gid & 15;
  int b = m >> 11, s = m & (S_LEN - 1);
  const float* orow = o_buf + ((size_t)(b * NH + h) * S_LEN + s) * DVV;
  float o0 = orow[lane], o1 = orow[lane + 64];
  float ss = o0 * o0 + o1 * o1;
#pragma unroll
  for (int off = 1; off < 64; off <<= 1) ss += __shfl_xor(ss, off);
  float r = rsqrtf(ss * (1.f / 128.f) + 1e-5f);
  size_t gi = (size_t)m * HID + h * DVV;
  float g0 = g_buf[gi + lane], g1 = g_buf[gi + lane + 64];
  og[gi + lane] = (_Float16)(o0 * r * nw[lane] * (g0 * sigmoidf_(g0)));
  og[gi + lane + 64] = (_Float16)(o1 * r * nw[lane + 64] * (g1 * sigmoidf_(g1)));
}

extern "C" void kernel_launch(void* const* d_in, const int* in_sizes, int n_in,
                              void* d_out, int out_size, void* d_ws, size_t ws_size,
                              hipStream_t stream) {
  const float* X      = (const float*)d_in[0];
  const float* qkv_w  = (const float*)d_in[1];
  const float* g_w    = (const float*)d_in[2];
  const float* b_w    = (const float*)d_in[3];
  const float* gk_w   = (const float*)d_in[4];
  const float* conv_w = (const float*)d_in[5];
  const float* norm_w = (const float*)d_in[6];
  const float* o_w    = (const float*)d_in[7];
  float* out = (float*)d_out;

  char* ws = (char*)d_ws;
  float* qkv_buf   = (float*)(ws);                          // 4096*3072*4 = 50331648
  float* qn        = (float*)(ws + 50331648);               // 4096*2048*4 = 33554432
  float* kn        = (float*)(ws + 83886080);               // 8388608
  float* vn        = (float*)(ws + 92274688);               // 8388608
  float* al        = (float*)(ws + 100663296);              // 262144
  float* be        = (float*)(ws + 100925440);              // 262144
  float* qkd       = (float*)(ws + 101187584);              // 262144
  float* o_buf     = (float*)(ws + 101449728);              // 33554432
  _Float16* X16    = (_Float16*)(ws + 135004160);           // 16777216
  _Float16* qw16   = (_Float16*)(ws + 151781376);           // 12582912
  _Float16* gw16   = (_Float16*)(ws + 164364288);           // 8388608
  float* g_buf     = qkv_buf;                               // reuse after conv
  _Float16* og16   = (_Float16*)(ws + 50331648);            // reuse qn after scan (16777216)
  _Float16* ow16   = (_Float16*)(ws + 50331648 + 16777216); // reuse qn after scan (8388608)

  dim3 blk(256);
  // f32->f16 conversions
  cvt_f16<<<dim3(4096), blk, 0, stream>>>(X, X16, 1048576);
  cvt_f16<<<dim3(3072), blk, 0, stream>>>(qkv_w, qw16, 786432);
  cvt_f16<<<dim3(2048), blk, 0, stream>>>(g_w, gw16, 524288);
  // 1) qkv projection (fp16 MFMA)
  gemm_bt_f16<<<dim3(QKV_DIM / 128, M_TOK / 128), blk, 0, stream>>>(X16, qw16, qkv_buf, M_TOK, QKV_DIM, HID);
  // 2) alpha/beta (fp32, precision-critical path into exp)
  gkb_kernel<<<dim3(M_TOK / 16), blk, 0, stream>>>(X, gk_w, b_w, al, be);
  // 3) conv + silu + l2norm + qk_dot (consumes qkv_buf)
  conv_kernel<<<dim3(M_TOK), blk, 0, stream>>>(qkv_buf, conv_w, qn, kn, vn, qkd);
  // 4) g projection (overwrites qkv_buf; conv done)
  gemm_bt_f16<<<dim3(HID / 128, M_TOK / 128), blk, 0, stream>>>(X16, gw16, g_buf, M_TOK, HID, HID);
  // 5) sequential gated delta scan
  scan_kernel<<<dim3(512), dim3(64), 0, stream>>>(qn, kn, vn, al, be, qkd, o_buf);
  // 6) o_w -> fp16 (into freed qn region; after scan)
  cvt_f16<<<dim3(2048), blk, 0, stream>>>(o_w, ow16, 524288);
  // 7) RMSNorm + gate -> og fp16 (into freed qn region)
  normgate_kernel<<<dim3(M_TOK * NH / 4), blk, 0, stream>>>(o_buf, g_buf, norm_w, og16);
  // 8) output projection (fp16 MFMA)
  gemm_bt_f16<<<dim3(HID / 128, M_TOK / 128), blk, 0, stream>>>(og16, ow16, out, M_TOK, HID, HID);
}